// Round 20
// baseline (306.911 us; speedup 1.0000x reference)
//
#include <hip/hip_runtime.h>
#include <cstdint>
#include <cstddef>

// Problem constants (match reference setup_inputs)
#define B_ 4
#define N_ 500
#define C_ 256
#define NH_ 8
#define DH_ 32
#define P_ 32
#define G_ 4
#define CG_ 64
#define BN_ (B_*N_)
#define QKV_QI 8
#define ANQ 16
#define ANB 32                 // ceil(500/16) query-tiles per (b,h)
#define ATT_BLKS (ANB * NH_ * B_)   // 1024

__constant__ const int LVL_W[4] = {128, 64, 32, 16};

static __device__ __forceinline__ unsigned short f2bf(float f) {
  union { float f; unsigned u; } v; v.f = f;
  unsigned r = v.u + 0x7FFF + ((v.u >> 16) & 1);  // RNE
  return (unsigned short)(r >> 16);
}
static __device__ __forceinline__ float bf2f(unsigned u16shifted) {
  union { unsigned u; float f; } v; v.u = u16shifted;
  return v.f;
}

// ---------------------------------------------------------------------------
// K0: fp32->bf16 transpose. 64ch x 256px tiles; 1KB contiguous reads; swizzled LDS.
__global__ __launch_bounds__(256) void mega_kernel(
    const float* __restrict__ f0, const float* __restrict__ f1,
    const float* __restrict__ f2, const float* __restrict__ f3,
    unsigned short* __restrict__ t0, unsigned short* __restrict__ t1,
    unsigned short* __restrict__ t2, unsigned short* __restrict__ t3) {
  __shared__ unsigned short tile[64][260];
  int blk = blockIdx.x;
  int t = threadIdx.x;
  const float* src; unsigned short* dst; int npix, i;
  if (blk < 1024)      { src = f0; dst = t0; npix = 16384; i = blk; }
  else if (blk < 1280) { src = f1; dst = t1; npix = 4096;  i = blk - 1024; }
  else if (blk < 1344) { src = f2; dst = t2; npix = 1024;  i = blk - 1280; }
  else                 { src = f3; dst = t3; npix = 256;   i = blk - 1344; }
  int pb = npix >> 8;                 // 256-px tiles per (b, chgrp)
  int px0 = (i % pb) * 256;
  int c0 = ((i / pb) & 3) * 64;
  int b  = i / (pb * 4);
  int lane = t & 63;
  int wv = t >> 6;
#pragma unroll
  for (int k = 0; k < 16; k++) {
    int r = k * 4 + wv;               // channel row 0..63
    float4 v = *(const float4*)&src[((size_t)b * C_ + c0 + r) * npix + px0 + lane * 4];
    ushort4 u;
    u.x = f2bf(v.x); u.y = f2bf(v.y); u.z = f2bf(v.z); u.w = f2bf(v.w);
    int col = (lane * 4) ^ (((r >> 4) & 3) << 2);   // swizzled px group
    *(ushort4*)&tile[r][col] = u;
  }
  __syncthreads();
  int cq = t & 15;
  int pr = t >> 4;                    // 0..15 block-wide
#pragma unroll
  for (int k = 0; k < 16; k++) {
    int p = k * 16 + pr;              // pixel 0..255
    ushort4 r4;
    {
      int ch = cq * 4;
      r4.x = tile[ch + 0][p ^ ((((ch + 0) >> 4) & 3) << 2)];
      r4.y = tile[ch + 1][p ^ ((((ch + 1) >> 4) & 3) << 2)];
      r4.z = tile[ch + 2][p ^ ((((ch + 2) >> 4) & 3) << 2)];
      r4.w = tile[ch + 3][p ^ ((((ch + 3) >> 4) & 3) << 2)];
    }
    *(ushort4*)&dst[((size_t)b * npix + px0 + p) * C_ + c0 + cq * 4] = r4;
  }
}

// ---------------------------------------------------------------------------
// K1: QKV projections with pe + box decode fused. 8 queries/block.
// q row-major; k transposed (attn phase-1 coalesced per-d loads); v row-major.
__global__ __launch_bounds__(256) void qkv_prep_kernel(
    const float* __restrict__ qcontent, const float* __restrict__ qbox,
    const float* __restrict__ Wq, const float* __restrict__ bq,
    const float* __restrict__ Wk, const float* __restrict__ bk,
    const float* __restrict__ Wv, const float* __restrict__ bv,
    float* __restrict__ x, float* __restrict__ boxd,
    float* __restrict__ q, float* __restrict__ kT, float* __restrict__ v) {
  __shared__ float xs[QKV_QI][C_];
  int blk = blockIdx.x;
  int t = threadIdx.x;
  int bn0 = blk * QKV_QI;
  int d = t >> 6;
  float tj = exp2f((float)((t >> 1) & 31) * 0.4152410f); // 10000^(j/32)
  float tmul = (d < 2) ? 0.001f : 1.0f;
  for (int i = 0; i < QKV_QI; i++) {
    float qv = qbox[(size_t)(bn0 + i) * 4 + d];
    float val = qv * tmul / tj;
    float pe = (t & 1) ? cosf(val) : sinf(val);
    float xv = qcontent[(size_t)(bn0 + i) * C_ + t] + pe;
    xs[i][t] = xv;
    x[(size_t)(bn0 + i) * C_ + t] = xv;
  }
  if (t < QKV_QI) {
    int bn = bn0 + t;
    const float* qb = qbox + (size_t)bn * 4;
    float cx = qb[0], cy = qb[1], z = qb[2], r = qb[3];
    float scale = exp2f(z);
    float w = scale * exp2f(-0.5f * r);
    float h = scale * exp2f(0.5f * r);
    float* bd = boxd + (size_t)bn * 12;
    float x1 = cx - 0.5f * w, y1 = cy - 0.5f * h, x2 = cx + 0.5f * w, y2 = cy + 0.5f * h;
    bd[0] = x1; bd[1] = y1; bd[2] = x2; bd[3] = y2;
    bd[4] = cx; bd[5] = cy; bd[6] = w; bd[7] = h; bd[8] = z;
    float area = fmaxf(x2 - x1, 0.f) * fmaxf(y2 - y1, 0.f);
    bd[9] = fmaxf(area, 1e-7f);
  }
  __syncthreads();
  float accq[QKV_QI], acck[QKV_QI], accv[QKV_QI];
  for (int i = 0; i < QKV_QI; i++) { accq[i] = 0.f; acck[i] = 0.f; accv[i] = 0.f; }
  const float4* wq4 = (const float4*)(Wq + (size_t)t * C_);
  const float4* wk4 = (const float4*)(Wk + (size_t)t * C_);
  const float4* wv4 = (const float4*)(Wv + (size_t)t * C_);
  for (int k4 = 0; k4 < C_ / 4; k4++) {
    float4 wq = wq4[k4], wk = wk4[k4], wv = wv4[k4];
    for (int i = 0; i < QKV_QI; i++) {
      float4 xv = *(const float4*)&xs[i][k4 * 4];
      accq[i] += xv.x * wq.x + xv.y * wq.y + xv.z * wq.z + xv.w * wq.w;
      acck[i] += xv.x * wk.x + xv.y * wk.y + xv.z * wk.z + xv.w * wk.w;
      accv[i] += xv.x * wv.x + xv.y * wv.y + xv.z * wv.z + xv.w * wv.w;
    }
  }
  for (int i = 0; i < QKV_QI; i++) {
    int bn = bn0 + i;
    int b = bn / N_;
    int n = bn % N_;
    q[(size_t)bn * C_ + t] = accq[i] + bq[t];
    kT[((size_t)b * C_ + t) * N_ + n] = acck[i] + bk[t];
    v[(size_t)bn * C_ + t] = accv[i] + bv[t];
  }
}

// ---------------------------------------------------------------------------
// K2: FUSED attention + copies, 512 threads (R20: doubles waves/CU 16->32 at
// the same 4 blocks/CU LDS cap; phase-1 single m pass, phase-2 2 queries/wave).
// blk < ATT_BLKS : attention for (bh = blk/ANB, n0 = (blk%ANB)*16)
// blk >= ATT_BLKS: float4 copies (512 threads x 2 f4 over 16KB regions)
__global__ __launch_bounds__(512, 8) void attn_copy_kernel(
    const float* __restrict__ q, const float* __restrict__ kT,
    const float* __restrict__ v, const float* __restrict__ boxd,
    const float* __restrict__ tau_p, float* __restrict__ ctx,
    const float* __restrict__ subxy, const float* __restrict__ subz,
    const float* __restrict__ subv,
    float* __restrict__ o_subxy, float* __restrict__ o_subz,
    float* __restrict__ o_subv) {
  __shared__ float pl[ANQ][512];      // 32 KB: scores, then p
  __shared__ float qs[ANQ][DH_];
  __shared__ float qb5[ANQ][5];
  __shared__ float redm[ANQ][8];
  __shared__ float reds[ANQ][8];
  int blk = blockIdx.x;
  int t = threadIdx.x;                // 0..511
  if (blk >= ATT_BLKS) {
    int cb = blk - ATT_BLKS;
    const float4* s4; float4* d4;
    if (cb < 125)      { s4 = (const float4*)subxy + (size_t)cb * 1024;
                         d4 = (float4*)o_subxy + (size_t)cb * 1024; }
    else if (cb < 375) { s4 = (const float4*)subz + (size_t)(cb - 125) * 1024;
                         d4 = (float4*)o_subz + (size_t)(cb - 125) * 1024; }
    else               { s4 = (const float4*)subv + (size_t)(cb - 375) * 1024;
                         d4 = (float4*)o_subv + (size_t)(cb - 375) * 1024; }
    d4[t] = s4[t];
    d4[t + 512] = s4[t + 512];
    return;
  }
  int n0 = (blk & (ANB - 1)) * ANQ;  // 0..496
  int bh = blk / ANB;
  int h = bh & 7;
  int b = bh >> 3;
  int nq = min(ANQ, N_ - n0);        // 16, or 4 for the tail tile

  {
    // stage 16q x 32d = 512 entries, one per thread
    int qq = t >> 5, dd = t & 31;
    int n = n0 + min(qq, nq - 1);
    qs[qq][dd] = q[((size_t)b * N_ + n) * C_ + h * DH_ + dd];
  }
  if (t < ANQ) {
    int n = n0 + min(t, nq - 1);
    const float* bd = boxd + ((size_t)b * N_ + n) * 12;
    qb5[t][0] = bd[0]; qb5[t][1] = bd[1]; qb5[t][2] = bd[2]; qb5[t][3] = bd[3];
    qb5[t][4] = 1.0f / bd[9];
  }
  __syncthreads();

  float tau = tau_p[h];
  const float scl = 0.17677669529663687f; // 32^-0.5
  int wv = t >> 6, lane = t & 63;

  // ---- Phase 1: scores for m = t (single pass; coalesced kT loads) ----
  float tmax[ANQ];
  {
    int m = t;
    int mc = min(m, N_ - 1);
    bool ok = m < N_;
    const float* kb = kT + ((size_t)b * C_ + h * DH_) * N_ + mc;
    float s[ANQ];
#pragma unroll
    for (int qq = 0; qq < ANQ; qq++) s[qq] = 0.f;
#pragma unroll
    for (int d = 0; d < DH_; d++) {
      float kd = kb[(size_t)d * N_];
#pragma unroll
      for (int qq = 0; qq < ANQ; qq++) s[qq] += qs[qq][d] * kd;
    }
    const float* bm = boxd + ((size_t)b * N_ + mc) * 12;
    float kx1 = bm[0], ky1 = bm[1], kx2 = bm[2], ky2 = bm[3];
#pragma unroll
    for (int qq = 0; qq < ANQ; qq++) {
      float iw = fmaxf(fminf(qb5[qq][2], kx2) - fmaxf(qb5[qq][0], kx1), 0.f);
      float ih = fmaxf(fminf(qb5[qq][3], ky2) - fmaxf(qb5[qq][1], ky1), 0.f);
      float bias = __logf(iw * ih * qb5[qq][4] + 1e-7f);
      float sc = ok ? (s[qq] * scl + bias * tau) : -1e30f;
      pl[qq][t] = sc;
      tmax[qq] = sc;
    }
  }
#pragma unroll
  for (int qq = 0; qq < ANQ; qq++) {
    float tm = tmax[qq];
#pragma unroll
    for (int off = 32; off >= 1; off >>= 1) tm = fmaxf(tm, __shfl_xor(tm, off, 64));
    if (lane == 0) redm[qq][wv] = tm;
  }
  __syncthreads();
  float mx[ANQ];
#pragma unroll
  for (int qq = 0; qq < ANQ; qq++) {
    float m0 = fmaxf(fmaxf(redm[qq][0], redm[qq][1]), fmaxf(redm[qq][2], redm[qq][3]));
    float m1 = fmaxf(fmaxf(redm[qq][4], redm[qq][5]), fmaxf(redm[qq][6], redm[qq][7]));
    mx[qq] = fmaxf(m0, m1);
  }
#pragma unroll
  for (int qq = 0; qq < ANQ; qq++) {
    float e0 = __expf(pl[qq][t] - mx[qq]);
    pl[qq][t] = e0;
    float s = e0;
#pragma unroll
    for (int off = 32; off >= 1; off >>= 1) s += __shfl_xor(s, off, 64);
    if (lane == 0) reds[qq][wv] = s;
  }
  __syncthreads();

  // ---- Phase 2: PV. Wave wv handles queries wv and wv+8. Lane = (c2, mq):
  // float2 v loads, 125-step m chain, each load serves 2 queries. ----
  int c2 = lane & 15;
  int mq = lane >> 4;
  const float2* vb2 = (const float2*)(v + ((size_t)b * N_) * C_ + h * DH_);
  const float* prow0 = pl[wv];
  const float* prow1 = pl[wv + 8];
  int mstart = mq * 125;
  int mend = mstart + 125;
  float ax0 = 0.f, ay0 = 0.f, ax1 = 0.f, ay1 = 0.f;
#pragma unroll 5
  for (int m = mstart; m < mend; m++) {
    float2 vv = vb2[(size_t)m * (C_ / 2) + c2];
    float p0 = prow0[m];
    float p1 = prow1[m];
    ax0 += p0 * vv.x; ay0 += p0 * vv.y;
    ax1 += p1 * vv.x; ay1 += p1 * vv.y;
  }
  ax0 += __shfl_xor(ax0, 16, 64); ax0 += __shfl_xor(ax0, 32, 64);
  ay0 += __shfl_xor(ay0, 16, 64); ay0 += __shfl_xor(ay0, 32, 64);
  ax1 += __shfl_xor(ax1, 16, 64); ax1 += __shfl_xor(ax1, 32, 64);
  ay1 += __shfl_xor(ay1, 16, 64); ay1 += __shfl_xor(ay1, 32, 64);
  if (mq == 0) {
    {
      int qq = wv;
      float inv = 1.0f / (reds[qq][0] + reds[qq][1] + reds[qq][2] + reds[qq][3] +
                          reds[qq][4] + reds[qq][5] + reds[qq][6] + reds[qq][7]);
      float2 o = {ax0 * inv, ay0 * inv};
      *(float2*)&ctx[((size_t)b * N_ + n0 + qq) * C_ + h * DH_ + c2 * 2] = o;
    }
    int qq1 = wv + 8;
    if (n0 + qq1 < N_) {
      float inv = 1.0f / (reds[qq1][0] + reds[qq1][1] + reds[qq1][2] + reds[qq1][3] +
                          reds[qq1][4] + reds[qq1][5] + reds[qq1][6] + reds[qq1][7]);
      float2 o = {ax1 * inv, ay1 * inv};
      *(float2*)&ctx[((size_t)b * N_ + n0 + qq1) * C_ + h * DH_ + c2 * 2] = o;
    }
  }
}

// ---------------------------------------------------------------------------
// K3: Wo projection + residual + layernorm + offset/scale heads, fused.
#define PQI 4
__global__ __launch_bounds__(256) void projln_head_kernel(
    const float* __restrict__ ctx, const float* __restrict__ x,
    const float* __restrict__ Wo, const float* __restrict__ bo,
    const float* __restrict__ ln_g, const float* __restrict__ ln_b,
    const float* __restrict__ boxd,
    const float* __restrict__ offW, const float* __restrict__ offb,
    const float* __restrict__ scW, const float* __restrict__ scb,
    float* __restrict__ qc_out,
    float* __restrict__ out_offset, float* __restrict__ out_sxy,
    float* __restrict__ out_sz, float* __restrict__ out_sl,
    float* __restrict__ zw_ws) {
  __shared__ float cs[PQI][C_];
  __shared__ float qs[PQI][C_];
  __shared__ float redbuf[PQI][8];
  int blk = blockIdx.x;
  int t = threadIdx.x;
  int bn0 = blk * PQI;
  for (int i = 0; i < PQI; i++) cs[i][t] = ctx[(size_t)(bn0 + i) * C_ + t];
  __syncthreads();
  float acc[PQI] = {0.f, 0.f, 0.f, 0.f};
  {
    const float4* w4 = (const float4*)(Wo + (size_t)t * C_);
    for (int k4 = 0; k4 < C_ / 4; k4++) {
      float4 w = w4[k4];
      for (int i = 0; i < PQI; i++) {
        float4 cv = *(const float4*)&cs[i][k4 * 4];
        acc[i] += cv.x * w.x + cv.y * w.y + cv.z * w.z + cv.w * w.w;
      }
    }
  }
  float y[PQI];
  int wave = t >> 6, lane = t & 63;
  for (int i = 0; i < PQI; i++) {
    y[i] = x[(size_t)(bn0 + i) * C_ + t] + acc[i] + bo[t];
    float s1 = y[i], s2 = y[i] * y[i];
#pragma unroll
    for (int off = 32; off >= 1; off >>= 1) {
      s1 += __shfl_xor(s1, off, 64);
      s2 += __shfl_xor(s2, off, 64);
    }
    if (lane == 0) { redbuf[i][wave] = s1; redbuf[i][wave + 4] = s2; }
  }
  __syncthreads();
  for (int i = 0; i < PQI; i++) {
    float s1 = redbuf[i][0] + redbuf[i][1] + redbuf[i][2] + redbuf[i][3];
    float s2 = redbuf[i][4] + redbuf[i][5] + redbuf[i][6] + redbuf[i][7];
    float mu = s1 * (1.0f / C_);
    float var = s2 * (1.0f / C_) - mu * mu;
    float inv = rsqrtf(var + 1e-5f);
    float o = (y[i] - mu) * inv * ln_g[t] + ln_b[t];
    qs[i][t] = o;
    qc_out[(size_t)(bn0 + i) * C_ + t] = o;
  }
  __syncthreads();
  float ao[PQI] = {0.f, 0.f, 0.f, 0.f};
  {
    const float4* w4 = (const float4*)(offW + (size_t)t * C_);
    for (int k4 = 0; k4 < C_ / 4; k4++) {
      float4 w = w4[k4];
      for (int i = 0; i < PQI; i++) {
        float4 cv = *(const float4*)&qs[i][k4 * 4];
        ao[i] += cv.x * w.x + cv.y * w.y + cv.z * w.z + cv.w * w.w;
      }
    }
  }
  int xy = t & 1;
  for (int i = 0; i < PQI; i++) {
    int bn = bn0 + i;
    const float* bd = boxd + (size_t)bn * 12;
    float off = ao[i] + offb[t];
    float ctr = xy ? bd[5] : bd[4];
    float wh = xy ? bd[7] : bd[6];
    float sxy = ctr + off * wh;
    out_offset[(size_t)bn * 256 + t] = off;
    out_sxy[(size_t)bn * 256 + t] = sxy;
  }
  if (t < 128) {
    float as[PQI] = {0.f, 0.f, 0.f, 0.f};
    const float4* sw4 = (const float4*)(scW + (size_t)t * C_);
    for (int k4 = 0; k4 < C_ / 4; k4++) {
      float4 w = sw4[k4];
      for (int i = 0; i < PQI; i++) {
        float4 cv = *(const float4*)&qs[i][k4 * 4];
        as[i] += cv.x * w.x + cv.y * w.y + cv.z * w.z + cv.w * w.w;
      }
    }
    for (int i = 0; i < PQI; i++) {
      int bn = bn0 + i;
      const float* bd = boxd + (size_t)bn * 12;
      float sl = as[i] + scb[t];
      float sz = sl + bd[8];
      out_sl[(size_t)bn * 128 + t] = sl;
      out_sz[(size_t)bn * 128 + t] = sz;
      float lvl = sz - 3.0f;
      float d1 = lvl - 1.f, d2 = lvl - 2.f, d3 = lvl - 3.f;
      float e0 = __expf(-0.5f * lvl * lvl);
      float e1 = __expf(-0.5f * d1 * d1);
      float e2 = __expf(-0.5f * d2 * d2);
      float e3 = __expf(-0.5f * d3 * d3);
      float inv = 1.0f / (e0 + e1 + e2 + e3);
      float* zw = zw_ws + ((size_t)bn * 128 + t) * 4;
      zw[0] = e0 * inv; zw[1] = e1 * inv; zw[2] = e2 * inv; zw[3] = e3 * inv;
    }
  }
}

// ---------------------------------------------------------------------------
// K4 v4: sampler on bf16 transposed feats. 8 lanes per point, uint4 = 8 bf16
// channels per lane (16B loads); 32 points per block.
__global__ __launch_bounds__(256) void sample_kernel_v4(
    const unsigned short* __restrict__ f0, const unsigned short* __restrict__ f1,
    const unsigned short* __restrict__ f2, const unsigned short* __restrict__ f3,
    const float* __restrict__ sxy, const float* __restrict__ zw_ws,
    float* __restrict__ out) {
  int t = threadIdx.x;
  int wv = t >> 6;
  int lane = t & 63;
  int sub = lane >> 3;   // point within wave (0..7)
  int c8 = lane & 7;     // channel octet within group
  int pt = blockIdx.x * 32 + wv * 8 + sub; // pt = bn*128 + p*4 + g
  int g = pt & 3;
  int p = (pt >> 2) & 31;
  int bn = pt >> 7;
  int b = bn / N_;

  float sx = sxy[(size_t)pt * 2];
  float sy = sxy[(size_t)pt * 2 + 1];
  const float* zw = zw_ws + (size_t)pt * 4;
  const unsigned short* feats[4] = {f0, f1, f2, f3};
  const float inv_stride[4] = {0.125f, 0.0625f, 0.03125f, 0.015625f};
  float acc0 = 0.f, acc1 = 0.f, acc2 = 0.f, acc3 = 0.f;
  float acc4 = 0.f, acc5 = 0.f, acc6 = 0.f, acc7 = 0.f;
#pragma unroll
  for (int l = 0; l < 4; l++) {
    float wl = zw[l];
    int W = LVL_W[l];
    float px = sx * inv_stride[l] - 0.5f;
    float py = sy * inv_stride[l] - 0.5f;
    float x0f = floorf(px), y0f = floorf(py);
    float fx = px - x0f, fy = py - y0f;
    int x0 = (int)x0f, y0 = (int)y0f;
    const unsigned short* fb = feats[l] + (size_t)b * W * W * C_ + g * CG_ + c8 * 8;
#pragma unroll
    for (int dy = 0; dy < 2; dy++) {
#pragma unroll
      for (int dx = 0; dx < 2; dx++) {
        int xi = x0 + dx, yi = y0 + dy;
        float valid = (xi >= 0 && xi < W && yi >= 0 && yi < W) ? 1.f : 0.f;
        int xc = min(max(xi, 0), W - 1);
        int yc = min(max(yi, 0), W - 1);
        float wgt = (dx ? fx : 1.f - fx) * (dy ? fy : 1.f - fy) * valid * wl;
        uint4 u = *(const uint4*)&fb[((size_t)yc * W + xc) * C_];
        acc0 += wgt * bf2f(u.x << 16);
        acc1 += wgt * bf2f(u.x & 0xFFFF0000u);
        acc2 += wgt * bf2f(u.y << 16);
        acc3 += wgt * bf2f(u.y & 0xFFFF0000u);
        acc4 += wgt * bf2f(u.z << 16);
        acc5 += wgt * bf2f(u.z & 0xFFFF0000u);
        acc6 += wgt * bf2f(u.w << 16);
        acc7 += wgt * bf2f(u.w & 0xFFFF0000u);
      }
    }
  }
  float* ob = &out[(size_t)bn * 8192 + g * 2048 + p * 64 + c8 * 8];
  float4 o0 = {acc0, acc1, acc2, acc3};
  float4 o1 = {acc4, acc5, acc6, acc7};
  *(float4*)&ob[0] = o0;
  *(float4*)&ob[4] = o1;
}

// Fallback: native-layout scalar sampler (used only if ws too small to transpose)
__global__ __launch_bounds__(256) void sample_kernel_native(
    const float* __restrict__ f0, const float* __restrict__ f1,
    const float* __restrict__ f2, const float* __restrict__ f3,
    const float* __restrict__ sxy, const float* __restrict__ zw_ws,
    float* __restrict__ out) {
  int t = threadIdx.x;
  int wv = t >> 6;
  int lane = t & 63;
  int pt = blockIdx.x * 4 + wv;
  int g = pt & 3;
  int p = (pt >> 2) & 31;
  int bn = pt >> 7;
  int b = bn / N_;
  float sx = sxy[(size_t)pt * 2];
  float sy = sxy[(size_t)pt * 2 + 1];
  const float* zw = zw_ws + (size_t)pt * 4;
  const float* feats[4] = {f0, f1, f2, f3};
  const float inv_stride[4] = {0.125f, 0.0625f, 0.03125f, 0.015625f};
  float acc = 0.f;
#pragma unroll
  for (int l = 0; l < 4; l++) {
    float wl = zw[l];
    int W = LVL_W[l];
    float px = sx * inv_stride[l] - 0.5f;
    float py = sy * inv_stride[l] - 0.5f;
    float x0f = floorf(px), y0f = floorf(py);
    float fx = px - x0f, fy = py - y0f;
    int x0 = (int)x0f, y0 = (int)y0f;
#pragma unroll
    for (int dy = 0; dy < 2; dy++) {
#pragma unroll
      for (int dx = 0; dx < 2; dx++) {
        int xi = x0 + dx, yi = y0 + dy;
        if (xi >= 0 && xi < W && yi >= 0 && yi < W) {
          float wgt = (dx ? fx : 1.f - fx) * (dy ? fy : 1.f - fy);
          float v = feats[l][(((size_t)b * C_ + g * CG_ + lane) * W + yi) * W + xi];
          acc += wgt * wl * v;
        }
      }
    }
  }
  out[(size_t)bn * 8192 + g * 2048 + p * 64 + lane] = acc;
}

// ---------------------------------------------------------------------------
extern "C" void kernel_launch(void* const* d_in, const int* in_sizes, int n_in,
                              void* d_out, int out_size, void* d_ws, size_t ws_size,
                              hipStream_t stream) {
  (void)in_sizes; (void)n_in; (void)out_size;
  const float* feat[4] = {(const float*)d_in[0], (const float*)d_in[1],
                          (const float*)d_in[2], (const float*)d_in[3]};
  const float* query_content = (const float*)d_in[4];
  const float* query_box = (const float*)d_in[5];
  const float* Wq = (const float*)d_in[10]; const float* bq = (const float*)d_in[11];
  const float* Wk = (const float*)d_in[12]; const float* bk = (const float*)d_in[13];
  const float* Wv = (const float*)d_in[14]; const float* bv = (const float*)d_in[15];
  const float* Wo = (const float*)d_in[16]; const float* bo = (const float*)d_in[17];
  const float* ln_g = (const float*)d_in[18]; const float* ln_b = (const float*)d_in[19];
  const float* offW = (const float*)d_in[20]; const float* offb = (const float*)d_in[21];
  const float* scW = (const float*)d_in[22]; const float* scb = (const float*)d_in[23];
  const float* iof_tau = (const float*)d_in[24];

  float* out = (float*)d_out;
  float* ws = (float*)d_ws;

  // output offsets (floats)
  const size_t O_FEATS = 0;            // 16,384,000
  const size_t O_SUBXY = 16384000;     //    512,000
  const size_t O_SUBZ = 16896000;      //  1,024,000
  const size_t O_SUBV = 17920000;      // 16,384,000
  const size_t O_QC = 34304000;        //    512,000
  const size_t O_SXY = 34816000;       //    512,000
  const size_t O_OFF = 35328000;       //    512,000
  const size_t O_SZ = 35840000;        //    256,000
  const size_t O_SL = 36096000;        //    256,000

  // workspace layout (floats)
  const size_t o_x = 0;                          // 512,000
  const size_t o_boxd = o_x + 512000;            //  24,000
  const size_t o_q = o_boxd + 24000;             // 512,000
  const size_t o_kT = o_q + 512000;              // 512,000
  const size_t o_v = o_kT + 512000;              // 512,000
  const size_t o_ctx = o_v + 512000;             // 512,000
  const size_t o_zw = o_ctx + 512000;            // 1,024,000
  const size_t o_ft = o_zw + 1024000;            // bf16 transposed feats (ushorts)
  const size_t ft_sz[4] = {16777216, 4194304, 1048576, 262144}; // ushort elements
  const size_t ft_total = ft_sz[0] + ft_sz[1] + ft_sz[2] + ft_sz[3];
  const size_t need_T = o_ft * sizeof(float) + ft_total * sizeof(unsigned short);
  const bool useT = ws_size >= need_T;

  unsigned short* ftu = (unsigned short*)(ws + o_ft);
  unsigned short* ftb[4] = {ftu,
                            ftu + ft_sz[0],
                            ftu + ft_sz[0] + ft_sz[1],
                            ftu + ft_sz[0] + ft_sz[1] + ft_sz[2]};

  // K0: feature transposes
  if (useT) {
    mega_kernel<<<1360, 256, 0, stream>>>(
        feat[0], feat[1], feat[2], feat[3],
        ftb[0], ftb[1], ftb[2], ftb[3]);
  }

  // K1: qkv + prep
  qkv_prep_kernel<<<BN_ / QKV_QI, 256, 0, stream>>>(
      query_content, query_box, Wq, bq, Wk, bk, Wv, bv,
      ws + o_x, ws + o_boxd, ws + o_q, ws + o_kT, ws + o_v);

  // K2: fused attention (512 threads, 16 queries/block) + passthrough copies
  attn_copy_kernel<<<ATT_BLKS + 4375, 512, 0, stream>>>(
      ws + o_q, ws + o_kT, ws + o_v, ws + o_boxd, iof_tau, ws + o_ctx,
      (const float*)d_in[6], (const float*)d_in[7], (const float*)d_in[8],
      out + O_SUBXY, out + O_SUBZ, out + O_SUBV);

  // K3: projection + LN + heads
  projln_head_kernel<<<BN_ / PQI, 256, 0, stream>>>(
      ws + o_ctx, ws + o_x, Wo, bo, ln_g, ln_b, ws + o_boxd,
      offW, offb, scW, scb,
      out + O_QC, out + O_OFF, out + O_SXY, out + O_SZ, out + O_SL,
      ws + o_zw);

  // K4: sampler (reads sample_xy from the output region)
  const int npoints = BN_ * P_ * G_; // 256,000
  if (useT) {
    sample_kernel_v4<<<npoints / 32, 256, 0, stream>>>(
        ftb[0], ftb[1], ftb[2], ftb[3],
        out + O_SXY, ws + o_zw, out + O_FEATS);
  } else {
    sample_kernel_native<<<npoints / 4, 256, 0, stream>>>(
        feat[0], feat[1], feat[2], feat[3],
        out + O_SXY, ws + o_zw, out + O_FEATS);
  }
}

// Round 21
// 243.002 us; speedup vs baseline: 1.2630x; 1.2630x over previous
//
#include <hip/hip_runtime.h>
#include <cstdint>
#include <cstddef>

// Problem constants (match reference setup_inputs)
#define B_ 4
#define N_ 500
#define C_ 256
#define NH_ 8
#define DH_ 32
#define P_ 32
#define G_ 4
#define CG_ 64
#define BN_ (B_*N_)
#define QKV_QI 8
#define ANQ 16
#define ANB 32                 // ceil(500/16) query-tiles per (b,h)
#define ATT_BLKS (ANB * NH_ * B_)   // 1024

__constant__ const int LVL_W[4] = {128, 64, 32, 16};

static __device__ __forceinline__ unsigned short f2bf(float f) {
  union { float f; unsigned u; } v; v.f = f;
  unsigned r = v.u + 0x7FFF + ((v.u >> 16) & 1);  // RNE
  return (unsigned short)(r >> 16);
}
static __device__ __forceinline__ float bf2f(unsigned u16shifted) {
  union { unsigned u; float f; } v; v.u = u16shifted;
  return v.f;
}

// ---------------------------------------------------------------------------
// K0: fp32->bf16 transpose. 64ch x 256px tiles; 1KB contiguous reads; swizzled LDS.
__global__ __launch_bounds__(256) void mega_kernel(
    const float* __restrict__ f0, const float* __restrict__ f1,
    const float* __restrict__ f2, const float* __restrict__ f3,
    unsigned short* __restrict__ t0, unsigned short* __restrict__ t1,
    unsigned short* __restrict__ t2, unsigned short* __restrict__ t3) {
  __shared__ unsigned short tile[64][260];
  int blk = blockIdx.x;
  int t = threadIdx.x;
  const float* src; unsigned short* dst; int npix, i;
  if (blk < 1024)      { src = f0; dst = t0; npix = 16384; i = blk; }
  else if (blk < 1280) { src = f1; dst = t1; npix = 4096;  i = blk - 1024; }
  else if (blk < 1344) { src = f2; dst = t2; npix = 1024;  i = blk - 1280; }
  else                 { src = f3; dst = t3; npix = 256;   i = blk - 1344; }
  int pb = npix >> 8;                 // 256-px tiles per (b, chgrp)
  int px0 = (i % pb) * 256;
  int c0 = ((i / pb) & 3) * 64;
  int b  = i / (pb * 4);
  int lane = t & 63;
  int wv = t >> 6;
#pragma unroll
  for (int k = 0; k < 16; k++) {
    int r = k * 4 + wv;               // channel row 0..63
    float4 v = *(const float4*)&src[((size_t)b * C_ + c0 + r) * npix + px0 + lane * 4];
    ushort4 u;
    u.x = f2bf(v.x); u.y = f2bf(v.y); u.z = f2bf(v.z); u.w = f2bf(v.w);
    int col = (lane * 4) ^ (((r >> 4) & 3) << 2);   // swizzled px group
    *(ushort4*)&tile[r][col] = u;
  }
  __syncthreads();
  int cq = t & 15;
  int pr = t >> 4;                    // 0..15 block-wide
#pragma unroll
  for (int k = 0; k < 16; k++) {
    int p = k * 16 + pr;              // pixel 0..255
    ushort4 r4;
    {
      int ch = cq * 4;
      r4.x = tile[ch + 0][p ^ ((((ch + 0) >> 4) & 3) << 2)];
      r4.y = tile[ch + 1][p ^ ((((ch + 1) >> 4) & 3) << 2)];
      r4.z = tile[ch + 2][p ^ ((((ch + 2) >> 4) & 3) << 2)];
      r4.w = tile[ch + 3][p ^ ((((ch + 3) >> 4) & 3) << 2)];
    }
    *(ushort4*)&dst[((size_t)b * npix + px0 + p) * C_ + c0 + cq * 4] = r4;
  }
}

// ---------------------------------------------------------------------------
// K1: QKV projections with pe + box decode fused. 8 queries/block.
// q row-major; k transposed (attn phase-1 coalesced per-d loads); v row-major.
__global__ __launch_bounds__(256) void qkv_prep_kernel(
    const float* __restrict__ qcontent, const float* __restrict__ qbox,
    const float* __restrict__ Wq, const float* __restrict__ bq,
    const float* __restrict__ Wk, const float* __restrict__ bk,
    const float* __restrict__ Wv, const float* __restrict__ bv,
    float* __restrict__ x, float* __restrict__ boxd,
    float* __restrict__ q, float* __restrict__ kT, float* __restrict__ v) {
  __shared__ float xs[QKV_QI][C_];
  int blk = blockIdx.x;
  int t = threadIdx.x;
  int bn0 = blk * QKV_QI;
  int d = t >> 6;
  float tj = exp2f((float)((t >> 1) & 31) * 0.4152410f); // 10000^(j/32)
  float tmul = (d < 2) ? 0.001f : 1.0f;
  for (int i = 0; i < QKV_QI; i++) {
    float qv = qbox[(size_t)(bn0 + i) * 4 + d];
    float val = qv * tmul / tj;
    float pe = (t & 1) ? cosf(val) : sinf(val);
    float xv = qcontent[(size_t)(bn0 + i) * C_ + t] + pe;
    xs[i][t] = xv;
    x[(size_t)(bn0 + i) * C_ + t] = xv;
  }
  if (t < QKV_QI) {
    int bn = bn0 + t;
    const float* qb = qbox + (size_t)bn * 4;
    float cx = qb[0], cy = qb[1], z = qb[2], r = qb[3];
    float scale = exp2f(z);
    float w = scale * exp2f(-0.5f * r);
    float h = scale * exp2f(0.5f * r);
    float* bd = boxd + (size_t)bn * 12;
    float x1 = cx - 0.5f * w, y1 = cy - 0.5f * h, x2 = cx + 0.5f * w, y2 = cy + 0.5f * h;
    bd[0] = x1; bd[1] = y1; bd[2] = x2; bd[3] = y2;
    bd[4] = cx; bd[5] = cy; bd[6] = w; bd[7] = h; bd[8] = z;
    float area = fmaxf(x2 - x1, 0.f) * fmaxf(y2 - y1, 0.f);
    bd[9] = fmaxf(area, 1e-7f);
  }
  __syncthreads();
  float accq[QKV_QI], acck[QKV_QI], accv[QKV_QI];
  for (int i = 0; i < QKV_QI; i++) { accq[i] = 0.f; acck[i] = 0.f; accv[i] = 0.f; }
  const float4* wq4 = (const float4*)(Wq + (size_t)t * C_);
  const float4* wk4 = (const float4*)(Wk + (size_t)t * C_);
  const float4* wv4 = (const float4*)(Wv + (size_t)t * C_);
  for (int k4 = 0; k4 < C_ / 4; k4++) {
    float4 wq = wq4[k4], wk = wk4[k4], wv = wv4[k4];
    for (int i = 0; i < QKV_QI; i++) {
      float4 xv = *(const float4*)&xs[i][k4 * 4];
      accq[i] += xv.x * wq.x + xv.y * wq.y + xv.z * wq.z + xv.w * wq.w;
      acck[i] += xv.x * wk.x + xv.y * wk.y + xv.z * wk.z + xv.w * wk.w;
      accv[i] += xv.x * wv.x + xv.y * wv.y + xv.z * wv.z + xv.w * wv.w;
    }
  }
  for (int i = 0; i < QKV_QI; i++) {
    int bn = bn0 + i;
    int b = bn / N_;
    int n = bn % N_;
    q[(size_t)bn * C_ + t] = accq[i] + bq[t];
    kT[((size_t)b * C_ + t) * N_ + n] = acck[i] + bk[t];
    v[(size_t)bn * C_ + t] = accv[i] + bv[t];
  }
}

// ---------------------------------------------------------------------------
// K2: FUSED attention + copies. ANQ=16 queries/block. Phase-2 lane =
// (channel-pair, m-quarter): float2 v loads, 125-step m chains,
// 2-step shfl reduce; float2 ctx stores. (R18 configuration — best known.)
__global__ __launch_bounds__(256) void attn_copy_kernel(
    const float* __restrict__ q, const float* __restrict__ kT,
    const float* __restrict__ v, const float* __restrict__ boxd,
    const float* __restrict__ tau_p, float* __restrict__ ctx,
    const float* __restrict__ subxy, const float* __restrict__ subz,
    const float* __restrict__ subv,
    float* __restrict__ o_subxy, float* __restrict__ o_subz,
    float* __restrict__ o_subv) {
  __shared__ float pl[ANQ][512];      // 32 KB: scores, then p
  __shared__ float qs[ANQ][DH_];
  __shared__ float qb5[ANQ][5];
  __shared__ float redm[ANQ][4];
  __shared__ float reds[ANQ][4];
  int blk = blockIdx.x;
  int t = threadIdx.x;
  if (blk >= ATT_BLKS) {
    int cb = blk - ATT_BLKS;
    const float4* s4; float4* d4;
    if (cb < 125)      { s4 = (const float4*)subxy + (size_t)cb * 1024;
                         d4 = (float4*)o_subxy + (size_t)cb * 1024; }
    else if (cb < 375) { s4 = (const float4*)subz + (size_t)(cb - 125) * 1024;
                         d4 = (float4*)o_subz + (size_t)(cb - 125) * 1024; }
    else               { s4 = (const float4*)subv + (size_t)(cb - 375) * 1024;
                         d4 = (float4*)o_subv + (size_t)(cb - 375) * 1024; }
    d4[t] = s4[t];
    d4[t + 256] = s4[t + 256];
    d4[t + 512] = s4[t + 512];
    d4[t + 768] = s4[t + 768];
    return;
  }
  int n0 = (blk & (ANB - 1)) * ANQ;  // 0..496
  int bh = blk / ANB;
  int h = bh & 7;
  int b = bh >> 3;
  int nq = min(ANQ, N_ - n0);        // 16, or 4 for the tail tile

  {
    // stage 16q x 32d = 512 entries with 256 threads (2 reps)
#pragma unroll
    for (int rep = 0; rep < 2; rep++) {
      int idx = rep * 256 + t;
      int qq = idx >> 5, dd = idx & 31;
      int n = n0 + min(qq, nq - 1);
      qs[qq][dd] = q[((size_t)b * N_ + n) * C_ + h * DH_ + dd];
    }
  }
  if (t < ANQ) {
    int n = n0 + min(t, nq - 1);
    const float* bd = boxd + ((size_t)b * N_ + n) * 12;
    qb5[t][0] = bd[0]; qb5[t][1] = bd[1]; qb5[t][2] = bd[2]; qb5[t][3] = bd[3];
    qb5[t][4] = 1.0f / bd[9];
  }
  __syncthreads();

  float tau = tau_p[h];
  const float scl = 0.17677669529663687f; // 32^-0.5
  float tmax[ANQ];
#pragma unroll
  for (int qq = 0; qq < ANQ; qq++) tmax[qq] = -1e30f;

  // ---- Phase 1: scores for m = t and m = t+256 (coalesced kT loads) ----
#pragma unroll
  for (int half = 0; half < 2; half++) {
    int m = t + half * 256;
    int mc = min(m, N_ - 1);
    bool ok = m < N_;
    const float* kb = kT + ((size_t)b * C_ + h * DH_) * N_ + mc;
    float s[ANQ];
#pragma unroll
    for (int qq = 0; qq < ANQ; qq++) s[qq] = 0.f;
#pragma unroll
    for (int d = 0; d < DH_; d++) {
      float kd = kb[(size_t)d * N_];
#pragma unroll
      for (int qq = 0; qq < ANQ; qq++) s[qq] += qs[qq][d] * kd;
    }
    const float* bm = boxd + ((size_t)b * N_ + mc) * 12;
    float kx1 = bm[0], ky1 = bm[1], kx2 = bm[2], ky2 = bm[3];
#pragma unroll
    for (int qq = 0; qq < ANQ; qq++) {
      float iw = fmaxf(fminf(qb5[qq][2], kx2) - fmaxf(qb5[qq][0], kx1), 0.f);
      float ih = fmaxf(fminf(qb5[qq][3], ky2) - fmaxf(qb5[qq][1], ky1), 0.f);
      float bias = __logf(iw * ih * qb5[qq][4] + 1e-7f);
      float sc = ok ? (s[qq] * scl + bias * tau) : -1e30f;
      pl[qq][t + half * 256] = sc;
      tmax[qq] = fmaxf(tmax[qq], sc);
    }
  }
  int wv = t >> 6, lane = t & 63;
#pragma unroll
  for (int qq = 0; qq < ANQ; qq++) {
    float tm = tmax[qq];
#pragma unroll
    for (int off = 32; off >= 1; off >>= 1) tm = fmaxf(tm, __shfl_xor(tm, off, 64));
    if (lane == 0) redm[qq][wv] = tm;
  }
  __syncthreads();
  float mx[ANQ];
#pragma unroll
  for (int qq = 0; qq < ANQ; qq++)
    mx[qq] = fmaxf(fmaxf(redm[qq][0], redm[qq][1]), fmaxf(redm[qq][2], redm[qq][3]));
  float psum[ANQ];
#pragma unroll
  for (int qq = 0; qq < ANQ; qq++) {
    float e0 = __expf(pl[qq][t] - mx[qq]);
    float e1 = __expf(pl[qq][t + 256] - mx[qq]);
    pl[qq][t] = e0;
    pl[qq][t + 256] = e1;
    psum[qq] = e0 + e1;
  }
#pragma unroll
  for (int qq = 0; qq < ANQ; qq++) {
    float s = psum[qq];
#pragma unroll
    for (int off = 32; off >= 1; off >>= 1) s += __shfl_xor(s, off, 64);
    if (lane == 0) reds[qq][wv] = s;
  }
  __syncthreads();

  // ---- Phase 2: PV. Lane = (channel-pair c2, m-quarter mq). float2 v loads,
  // 125-step m chain, 4 queries per wave (wv, wv+4, wv+8, wv+12). ----
  int c2 = lane & 15;
  int mq = lane >> 4;
  const float2* vb2 = (const float2*)(v + ((size_t)b * N_) * C_ + h * DH_);
  const float* prow[4] = {pl[wv], pl[wv + 4], pl[wv + 8], pl[wv + 12]};
  int mstart = mq * 125;
  int mend = mstart + 125;
  float accx[4] = {0.f, 0.f, 0.f, 0.f};
  float accy[4] = {0.f, 0.f, 0.f, 0.f};
#pragma unroll 5
  for (int m = mstart; m < mend; m++) {
    float2 vv = vb2[(size_t)m * (C_ / 2) + c2];
#pragma unroll
    for (int j = 0; j < 4; j++) {
      float p = prow[j][m];
      accx[j] += p * vv.x;
      accy[j] += p * vv.y;
    }
  }
#pragma unroll
  for (int j = 0; j < 4; j++) {
    float ax = accx[j], ay = accy[j];
    ax += __shfl_xor(ax, 16, 64);
    ax += __shfl_xor(ax, 32, 64);
    ay += __shfl_xor(ay, 16, 64);
    ay += __shfl_xor(ay, 32, 64);
    int qq = wv + j * 4;
    if (mq == 0 && n0 + qq < N_) {
      float inv = 1.0f / (reds[qq][0] + reds[qq][1] + reds[qq][2] + reds[qq][3]);
      float2 o = {ax * inv, ay * inv};
      *(float2*)&ctx[((size_t)b * N_ + n0 + qq) * C_ + h * DH_ + c2 * 2] = o;
    }
  }
}

// ---------------------------------------------------------------------------
// K3: Wo projection + residual + layernorm + offset/scale heads, fused.
#define PQI 4
__global__ __launch_bounds__(256) void projln_head_kernel(
    const float* __restrict__ ctx, const float* __restrict__ x,
    const float* __restrict__ Wo, const float* __restrict__ bo,
    const float* __restrict__ ln_g, const float* __restrict__ ln_b,
    const float* __restrict__ boxd,
    const float* __restrict__ offW, const float* __restrict__ offb,
    const float* __restrict__ scW, const float* __restrict__ scb,
    float* __restrict__ qc_out,
    float* __restrict__ out_offset, float* __restrict__ out_sxy,
    float* __restrict__ out_sz, float* __restrict__ out_sl,
    float* __restrict__ zw_ws) {
  __shared__ float cs[PQI][C_];
  __shared__ float qs[PQI][C_];
  __shared__ float redbuf[PQI][8];
  int blk = blockIdx.x;
  int t = threadIdx.x;
  int bn0 = blk * PQI;
  for (int i = 0; i < PQI; i++) cs[i][t] = ctx[(size_t)(bn0 + i) * C_ + t];
  __syncthreads();
  float acc[PQI] = {0.f, 0.f, 0.f, 0.f};
  {
    const float4* w4 = (const float4*)(Wo + (size_t)t * C_);
    for (int k4 = 0; k4 < C_ / 4; k4++) {
      float4 w = w4[k4];
      for (int i = 0; i < PQI; i++) {
        float4 cv = *(const float4*)&cs[i][k4 * 4];
        acc[i] += cv.x * w.x + cv.y * w.y + cv.z * w.z + cv.w * w.w;
      }
    }
  }
  float y[PQI];
  int wave = t >> 6, lane = t & 63;
  for (int i = 0; i < PQI; i++) {
    y[i] = x[(size_t)(bn0 + i) * C_ + t] + acc[i] + bo[t];
    float s1 = y[i], s2 = y[i] * y[i];
#pragma unroll
    for (int off = 32; off >= 1; off >>= 1) {
      s1 += __shfl_xor(s1, off, 64);
      s2 += __shfl_xor(s2, off, 64);
    }
    if (lane == 0) { redbuf[i][wave] = s1; redbuf[i][wave + 4] = s2; }
  }
  __syncthreads();
  for (int i = 0; i < PQI; i++) {
    float s1 = redbuf[i][0] + redbuf[i][1] + redbuf[i][2] + redbuf[i][3];
    float s2 = redbuf[i][4] + redbuf[i][5] + redbuf[i][6] + redbuf[i][7];
    float mu = s1 * (1.0f / C_);
    float var = s2 * (1.0f / C_) - mu * mu;
    float inv = rsqrtf(var + 1e-5f);
    float o = (y[i] - mu) * inv * ln_g[t] + ln_b[t];
    qs[i][t] = o;
    qc_out[(size_t)(bn0 + i) * C_ + t] = o;
  }
  __syncthreads();
  float ao[PQI] = {0.f, 0.f, 0.f, 0.f};
  {
    const float4* w4 = (const float4*)(offW + (size_t)t * C_);
    for (int k4 = 0; k4 < C_ / 4; k4++) {
      float4 w = w4[k4];
      for (int i = 0; i < PQI; i++) {
        float4 cv = *(const float4*)&qs[i][k4 * 4];
        ao[i] += cv.x * w.x + cv.y * w.y + cv.z * w.z + cv.w * w.w;
      }
    }
  }
  int xy = t & 1;
  for (int i = 0; i < PQI; i++) {
    int bn = bn0 + i;
    const float* bd = boxd + (size_t)bn * 12;
    float off = ao[i] + offb[t];
    float ctr = xy ? bd[5] : bd[4];
    float wh = xy ? bd[7] : bd[6];
    float sxy = ctr + off * wh;
    out_offset[(size_t)bn * 256 + t] = off;
    out_sxy[(size_t)bn * 256 + t] = sxy;
  }
  if (t < 128) {
    float as[PQI] = {0.f, 0.f, 0.f, 0.f};
    const float4* sw4 = (const float4*)(scW + (size_t)t * C_);
    for (int k4 = 0; k4 < C_ / 4; k4++) {
      float4 w = sw4[k4];
      for (int i = 0; i < PQI; i++) {
        float4 cv = *(const float4*)&qs[i][k4 * 4];
        as[i] += cv.x * w.x + cv.y * w.y + cv.z * w.z + cv.w * w.w;
      }
    }
    for (int i = 0; i < PQI; i++) {
      int bn = bn0 + i;
      const float* bd = boxd + (size_t)bn * 12;
      float sl = as[i] + scb[t];
      float sz = sl + bd[8];
      out_sl[(size_t)bn * 128 + t] = sl;
      out_sz[(size_t)bn * 128 + t] = sz;
      float lvl = sz - 3.0f;
      float d1 = lvl - 1.f, d2 = lvl - 2.f, d3 = lvl - 3.f;
      float e0 = __expf(-0.5f * lvl * lvl);
      float e1 = __expf(-0.5f * d1 * d1);
      float e2 = __expf(-0.5f * d2 * d2);
      float e3 = __expf(-0.5f * d3 * d3);
      float inv = 1.0f / (e0 + e1 + e2 + e3);
      float* zw = zw_ws + ((size_t)bn * 128 + t) * 4;
      zw[0] = e0 * inv; zw[1] = e1 * inv; zw[2] = e2 * inv; zw[3] = e3 * inv;
    }
  }
}

// ---------------------------------------------------------------------------
// K4 v4: sampler on bf16 transposed feats. 8 lanes per point, uint4 = 8 bf16
// channels per lane (16B loads); 32 points per block.
__global__ __launch_bounds__(256) void sample_kernel_v4(
    const unsigned short* __restrict__ f0, const unsigned short* __restrict__ f1,
    const unsigned short* __restrict__ f2, const unsigned short* __restrict__ f3,
    const float* __restrict__ sxy, const float* __restrict__ zw_ws,
    float* __restrict__ out) {
  int t = threadIdx.x;
  int wv = t >> 6;
  int lane = t & 63;
  int sub = lane >> 3;   // point within wave (0..7)
  int c8 = lane & 7;     // channel octet within group
  int pt = blockIdx.x * 32 + wv * 8 + sub; // pt = bn*128 + p*4 + g
  int g = pt & 3;
  int p = (pt >> 2) & 31;
  int bn = pt >> 7;
  int b = bn / N_;

  float sx = sxy[(size_t)pt * 2];
  float sy = sxy[(size_t)pt * 2 + 1];
  const float* zw = zw_ws + (size_t)pt * 4;
  const unsigned short* feats[4] = {f0, f1, f2, f3};
  const float inv_stride[4] = {0.125f, 0.0625f, 0.03125f, 0.015625f};
  float acc0 = 0.f, acc1 = 0.f, acc2 = 0.f, acc3 = 0.f;
  float acc4 = 0.f, acc5 = 0.f, acc6 = 0.f, acc7 = 0.f;
#pragma unroll
  for (int l = 0; l < 4; l++) {
    float wl = zw[l];
    int W = LVL_W[l];
    float px = sx * inv_stride[l] - 0.5f;
    float py = sy * inv_stride[l] - 0.5f;
    float x0f = floorf(px), y0f = floorf(py);
    float fx = px - x0f, fy = py - y0f;
    int x0 = (int)x0f, y0 = (int)y0f;
    const unsigned short* fb = feats[l] + (size_t)b * W * W * C_ + g * CG_ + c8 * 8;
#pragma unroll
    for (int dy = 0; dy < 2; dy++) {
#pragma unroll
      for (int dx = 0; dx < 2; dx++) {
        int xi = x0 + dx, yi = y0 + dy;
        float valid = (xi >= 0 && xi < W && yi >= 0 && yi < W) ? 1.f : 0.f;
        int xc = min(max(xi, 0), W - 1);
        int yc = min(max(yi, 0), W - 1);
        float wgt = (dx ? fx : 1.f - fx) * (dy ? fy : 1.f - fy) * valid * wl;
        uint4 u = *(const uint4*)&fb[((size_t)yc * W + xc) * C_];
        acc0 += wgt * bf2f(u.x << 16);
        acc1 += wgt * bf2f(u.x & 0xFFFF0000u);
        acc2 += wgt * bf2f(u.y << 16);
        acc3 += wgt * bf2f(u.y & 0xFFFF0000u);
        acc4 += wgt * bf2f(u.z << 16);
        acc5 += wgt * bf2f(u.z & 0xFFFF0000u);
        acc6 += wgt * bf2f(u.w << 16);
        acc7 += wgt * bf2f(u.w & 0xFFFF0000u);
      }
    }
  }
  float* ob = &out[(size_t)bn * 8192 + g * 2048 + p * 64 + c8 * 8];
  float4 o0 = {acc0, acc1, acc2, acc3};
  float4 o1 = {acc4, acc5, acc6, acc7};
  *(float4*)&ob[0] = o0;
  *(float4*)&ob[4] = o1;
}

// Fallback: native-layout scalar sampler (used only if ws too small to transpose)
__global__ __launch_bounds__(256) void sample_kernel_native(
    const float* __restrict__ f0, const float* __restrict__ f1,
    const float* __restrict__ f2, const float* __restrict__ f3,
    const float* __restrict__ sxy, const float* __restrict__ zw_ws,
    float* __restrict__ out) {
  int t = threadIdx.x;
  int wv = t >> 6;
  int lane = t & 63;
  int pt = blockIdx.x * 4 + wv;
  int g = pt & 3;
  int p = (pt >> 2) & 31;
  int bn = pt >> 7;
  int b = bn / N_;
  float sx = sxy[(size_t)pt * 2];
  float sy = sxy[(size_t)pt * 2 + 1];
  const float* zw = zw_ws + (size_t)pt * 4;
  const float* feats[4] = {f0, f1, f2, f3};
  const float inv_stride[4] = {0.125f, 0.0625f, 0.03125f, 0.015625f};
  float acc = 0.f;
#pragma unroll
  for (int l = 0; l < 4; l++) {
    float wl = zw[l];
    int W = LVL_W[l];
    float px = sx * inv_stride[l] - 0.5f;
    float py = sy * inv_stride[l] - 0.5f;
    float x0f = floorf(px), y0f = floorf(py);
    float fx = px - x0f, fy = py - y0f;
    int x0 = (int)x0f, y0 = (int)y0f;
#pragma unroll
    for (int dy = 0; dy < 2; dy++) {
#pragma unroll
      for (int dx = 0; dx < 2; dx++) {
        int xi = x0 + dx, yi = y0 + dy;
        if (xi >= 0 && xi < W && yi >= 0 && yi < W) {
          float wgt = (dx ? fx : 1.f - fx) * (dy ? fy : 1.f - fy);
          float v = feats[l][(((size_t)b * C_ + g * CG_ + lane) * W + yi) * W + xi];
          acc += wgt * wl * v;
        }
      }
    }
  }
  out[(size_t)bn * 8192 + g * 2048 + p * 64 + lane] = acc;
}

// ---------------------------------------------------------------------------
extern "C" void kernel_launch(void* const* d_in, const int* in_sizes, int n_in,
                              void* d_out, int out_size, void* d_ws, size_t ws_size,
                              hipStream_t stream) {
  (void)in_sizes; (void)n_in; (void)out_size;
  const float* feat[4] = {(const float*)d_in[0], (const float*)d_in[1],
                          (const float*)d_in[2], (const float*)d_in[3]};
  const float* query_content = (const float*)d_in[4];
  const float* query_box = (const float*)d_in[5];
  const float* Wq = (const float*)d_in[10]; const float* bq = (const float*)d_in[11];
  const float* Wk = (const float*)d_in[12]; const float* bk = (const float*)d_in[13];
  const float* Wv = (const float*)d_in[14]; const float* bv = (const float*)d_in[15];
  const float* Wo = (const float*)d_in[16]; const float* bo = (const float*)d_in[17];
  const float* ln_g = (const float*)d_in[18]; const float* ln_b = (const float*)d_in[19];
  const float* offW = (const float*)d_in[20]; const float* offb = (const float*)d_in[21];
  const float* scW = (const float*)d_in[22]; const float* scb = (const float*)d_in[23];
  const float* iof_tau = (const float*)d_in[24];

  float* out = (float*)d_out;
  float* ws = (float*)d_ws;

  // output offsets (floats)
  const size_t O_FEATS = 0;            // 16,384,000
  const size_t O_SUBXY = 16384000;     //    512,000
  const size_t O_SUBZ = 16896000;      //  1,024,000
  const size_t O_SUBV = 17920000;      // 16,384,000
  const size_t O_QC = 34304000;        //    512,000
  const size_t O_SXY = 34816000;       //    512,000
  const size_t O_OFF = 35328000;       //    512,000
  const size_t O_SZ = 35840000;        //    256,000
  const size_t O_SL = 36096000;        //    256,000

  // workspace layout (floats)
  const size_t o_x = 0;                          // 512,000
  const size_t o_boxd = o_x + 512000;            //  24,000
  const size_t o_q = o_boxd + 24000;             // 512,000
  const size_t o_kT = o_q + 512000;              // 512,000
  const size_t o_v = o_kT + 512000;              // 512,000
  const size_t o_ctx = o_v + 512000;             // 512,000
  const size_t o_zw = o_ctx + 512000;            // 1,024,000
  const size_t o_ft = o_zw + 1024000;            // bf16 transposed feats (ushorts)
  const size_t ft_sz[4] = {16777216, 4194304, 1048576, 262144}; // ushort elements
  const size_t ft_total = ft_sz[0] + ft_sz[1] + ft_sz[2] + ft_sz[3];
  const size_t need_T = o_ft * sizeof(float) + ft_total * sizeof(unsigned short);
  const bool useT = ws_size >= need_T;

  unsigned short* ftu = (unsigned short*)(ws + o_ft);
  unsigned short* ftb[4] = {ftu,
                            ftu + ft_sz[0],
                            ftu + ft_sz[0] + ft_sz[1],
                            ftu + ft_sz[0] + ft_sz[1] + ft_sz[2]};

  // K0: feature transposes
  if (useT) {
    mega_kernel<<<1360, 256, 0, stream>>>(
        feat[0], feat[1], feat[2], feat[3],
        ftb[0], ftb[1], ftb[2], ftb[3]);
  }

  // K1: qkv + prep
  qkv_prep_kernel<<<BN_ / QKV_QI, 256, 0, stream>>>(
      query_content, query_box, Wq, bq, Wk, bk, Wv, bv,
      ws + o_x, ws + o_boxd, ws + o_q, ws + o_kT, ws + o_v);

  // K2: fused attention (S in LDS, 16 queries/block) + passthrough copies
  attn_copy_kernel<<<ATT_BLKS + 4375, 256, 0, stream>>>(
      ws + o_q, ws + o_kT, ws + o_v, ws + o_boxd, iof_tau, ws + o_ctx,
      (const float*)d_in[6], (const float*)d_in[7], (const float*)d_in[8],
      out + O_SUBXY, out + O_SUBZ, out + O_SUBV);

  // K3: projection + LN + heads
  projln_head_kernel<<<BN_ / PQI, 256, 0, stream>>>(
      ws + o_ctx, ws + o_x, Wo, bo, ln_g, ln_b, ws + o_boxd,
      offW, offb, scW, scb,
      out + O_QC, out + O_OFF, out + O_SXY, out + O_SZ, out + O_SL,
      ws + o_zw);

  // K4: sampler (reads sample_xy from the output region)
  const int npoints = BN_ * P_ * G_; // 256,000
  if (useT) {
    sample_kernel_v4<<<npoints / 32, 256, 0, stream>>>(
        ftb[0], ftb[1], ftb[2], ftb[3],
        out + O_SXY, ws + o_zw, out + O_FEATS);
  } else {
    sample_kernel_native<<<npoints / 4, 256, 0, stream>>>(
        feat[0], feat[1], feat[2], feat[3],
        out + O_SXY, ws + o_zw, out + O_FEATS);
  }
}